// Round 7
// baseline (352.549 us; speedup 1.0000x reference)
//
#include <hip/hip_runtime.h>
#include <math.h>

// Problem constants (fixed by reference)
#define NR 2048
#define MC 131072
#define DIM 64
#define KSEL 11                    // k+1 smallest kept per row
#define PPART 64                   // column partitions
#define PART_COLS (MC / PPART)     // 2048 cols per partition
#define CHUNK 128                  // cols per drain period
#define NCHUNK (PART_COLS / CHUNK) // 16
#define ROWS_PER_BLOCK 64          // 4 waves x 16 rows
#define QSTR 34                    // queue stride in halves = 17 dwords (odd -> all 32 banks)

typedef _Float16 v8h __attribute__((ext_vector_type(8)));
typedef _Float16 v2h __attribute__((ext_vector_type(2)));
typedef float v4f __attribute__((ext_vector_type(4)));

// ---------------- prep: bnorm (fp32) + buf -> f16 ----------------
__global__ __launch_bounds__(256) void k_prep_b(const float* __restrict__ buf,
                                                _Float16* __restrict__ B16,
                                                float* __restrict__ bnorm) {
  int gid = blockIdx.x * 256 + threadIdx.x;   // 4 threads per buffer row
  int row = gid >> 2, q = gid & 3;
  const float4* src = (const float4*)(buf + (size_t)row * DIM + q * 16);
  float4 f0 = src[0], f1 = src[1], f2 = src[2], f3 = src[3];
  float s = f0.x*f0.x + f0.y*f0.y + f0.z*f0.z + f0.w*f0.w
          + f1.x*f1.x + f1.y*f1.y + f1.z*f1.z + f1.w*f1.w
          + f2.x*f2.x + f2.y*f2.y + f2.z*f2.z + f2.w*f2.w
          + f3.x*f3.x + f3.y*f3.y + f3.z*f3.z + f3.w*f3.w;
  s += __shfl_xor(s, 1);
  s += __shfl_xor(s, 2);
  if (q == 0) bnorm[row] = s;
  union { _Float16 h[16]; uint4 u[2]; } o;
  o.h[0]=(_Float16)f0.x; o.h[1]=(_Float16)f0.y; o.h[2]=(_Float16)f0.z; o.h[3]=(_Float16)f0.w;
  o.h[4]=(_Float16)f1.x; o.h[5]=(_Float16)f1.y; o.h[6]=(_Float16)f1.z; o.h[7]=(_Float16)f1.w;
  o.h[8]=(_Float16)f2.x; o.h[9]=(_Float16)f2.y; o.h[10]=(_Float16)f2.z; o.h[11]=(_Float16)f2.w;
  o.h[12]=(_Float16)f3.x; o.h[13]=(_Float16)f3.y; o.h[14]=(_Float16)f3.z; o.h[15]=(_Float16)f3.w;
  uint4* dst = (uint4*)(B16 + (size_t)row * DIM + q * 16);
  dst[0] = o.u[0]; dst[1] = o.u[1];
}

// branchless bubble-insert into sorted-ascending 11-list. Inserting any value
// >= lst[10] (incl. +inf) is a no-op (it bubbles off the end). 22 min/max ops.
__device__ __forceinline__ void bins11(float v, float lst[KSEL]) {
  float t = v;
#pragma unroll
  for (int j = 0; j < KSEL; ++j) {
    float a = fminf(lst[j], t);
    t = fmaxf(lst[j], t);
    lst[j] = a;
  }
}

// ---------------- main: barrier-free MFMA + f16 queue + sorted top-11 --------
// D = A(bufcols) x B(xrows). B16 row-major [col][k] IS the A-fragment layout:
// lane loads 16B straight from global (no LDS staging, no __syncthreads).
// Waves are fully independent; LDS holds only the per-lane candidate queue.
__global__ __launch_bounds__(256) void k_main(const float* __restrict__ x,
                                              const _Float16* __restrict__ B16,
                                              const float* __restrict__ bnorm,
                                              float* __restrict__ cand) {
  __shared__ __align__(8) _Float16 qmem[4][64 * QSTR];   // 17408 B total

  const int tid = threadIdx.x;
  const int w = tid >> 6, lane = tid & 63;
  const int quad = lane >> 4, l15 = lane & 15;
  const int row = blockIdx.y * ROWS_PER_BLOCK + w * 16 + l15;  // this lane's x-row
  const int pbase = blockIdx.x * PART_COLS;
  _Float16* q = &qmem[w][lane * QSTR];

  // x fragments (B-operand: B[k = quad*8+j + 32ks][n = l15]) + exact fp32 norm
  v8h bx0, bx1;
  float xn;
  {
    const float* xr = x + (size_t)row * DIM;
    const float4* xp0 = (const float4*)(xr + quad * 8);
    float4 a0 = xp0[0], a1 = xp0[1];
    const float4* xp1 = (const float4*)(xr + 32 + quad * 8);
    float4 c0 = xp1[0], c1 = xp1[1];
    v8h h0, h1;
    h0[0]=(_Float16)a0.x; h0[1]=(_Float16)a0.y; h0[2]=(_Float16)a0.z; h0[3]=(_Float16)a0.w;
    h0[4]=(_Float16)a1.x; h0[5]=(_Float16)a1.y; h0[6]=(_Float16)a1.z; h0[7]=(_Float16)a1.w;
    h1[0]=(_Float16)c0.x; h1[1]=(_Float16)c0.y; h1[2]=(_Float16)c0.z; h1[3]=(_Float16)c0.w;
    h1[4]=(_Float16)c1.x; h1[5]=(_Float16)c1.y; h1[6]=(_Float16)c1.z; h1[7]=(_Float16)c1.w;
    bx0 = h0; bx1 = h1;
    float s = a0.x*a0.x + a0.y*a0.y + a0.z*a0.z + a0.w*a0.w
            + a1.x*a1.x + a1.y*a1.y + a1.z*a1.z + a1.w*a1.w
            + c0.x*c0.x + c0.y*c0.y + c0.z*c0.z + c0.w*c0.w
            + c1.x*c1.x + c1.y*c1.y + c1.z*c1.z + c1.w*c1.w;
    s += __shfl_xor(s, 16);   // each quad holds a disjoint 16 of the 64 k's
    s += __shfl_xor(s, 32);
    xn = s;
  }

  float lst[KSEL];   // sorted ascending; lst[10] = private threshold
#pragma unroll
  for (int i = 0; i < KSEL; ++i) lst[i] = __builtin_inff();
  float thrx = __builtin_inff();   // (shared row thr) - xn, for the scan compare

  for (int c = 0; c < NCHUNK; ++c) {
    const int cb = pbase + c * CHUNK;
    int qo = 0;   // queue write index (elements)
#pragma unroll 4
    for (int mt = 0; mt < 8; ++mt) {
      const int col = cb + mt * 16;
      // A-fragment directly from global: contiguous 16B per lane, 16B-aligned
      const _Float16* bp = B16 + (size_t)(col + l15) * DIM + quad * 8;
      v8h a0 = *(const v8h*)bp;
      v8h a1 = *(const v8h*)(bp + 32);
      float4 bn4 = *(const float4*)(bnorm + col + quad * 4);
      v4f acc = (v4f)(0.0f);
      acc = __builtin_amdgcn_mfma_f32_16x16x32_f16(a0, bx0, acc, 0, 0, 0);
      acc = __builtin_amdgcn_mfma_f32_16x16x32_f16(a1, bx1, acc, 0, 0, 0);
#pragma unroll
      for (int reg = 0; reg < 4; ++reg) {
        float bn = (reg == 0) ? bn4.x : (reg == 1) ? bn4.y : (reg == 2) ? bn4.z : bn4.w;
        float t = fmaf(acc[reg], -2.0f, bn);   // d2 = t + xn
        // branchless push: always write; advance only on pass. Garbage slots
        // are overwritten by later pushes and bounds-guarded at drain.
        q[qo] = (_Float16)t;
        qo += (t < thrx) ? 1 : 0;
      }
    }

    // batched drain: 4 halves per iter via two dword-aligned ds_read_b32
    for (int i = 0; __ballot(i < qo); i += 4) {
      v2h p0 = *(const v2h*)(q + i);       // addr = lane*68 + 2i, dword-aligned
      v2h p1 = *(const v2h*)(q + i + 2);
      float v0 = (float)p0[0] + xn, v1 = (float)p0[1] + xn;
      float v2 = (float)p1[0] + xn, v3 = (float)p1[1] + xn;
      v0 = (i + 0 < qo) ? v0 : __builtin_inff();
      v1 = (i + 1 < qo) ? v1 : __builtin_inff();
      v2 = (i + 2 < qo) ? v2 : __builtin_inff();
      v3 = (i + 3 < qo) ? v3 : __builtin_inff();
      float m = fminf(fminf(v0, v1), fminf(v2, v3));
      if (__ballot(m < lst[KSEL - 1])) {   // any lane improves its list?
        bins11(v0, lst); bins11(v1, lst);  // v >= lst[10] inserts are no-ops
        bins11(v2, lst); bins11(v3, lst);
      }
    }

    // tighten shared threshold: min over the 4 quads holding this row
    float t = fminf(lst[KSEL - 1], __shfl_xor(lst[KSEL - 1], 16));
    thrx = fminf(t, __shfl_xor(t, 32)) - xn;
  }

  // merge the 4 quads' sorted lists (disjoint col subsets of the same row)
#pragma unroll
  for (int s = 16; s <= 32; s <<= 1) {
    float other[KSEL];
#pragma unroll
    for (int j = 0; j < KSEL; ++j) other[j] = __shfl_xor(lst[j], s);
#pragma unroll
    for (int j = 0; j < KSEL; ++j) bins11(other[j], lst);
  }

  if (quad == 0) {   // one writer per row: cand layout [row][part][k], sorted
    float* dst = cand + (size_t)row * (PPART * KSEL) + blockIdx.x * KSEL;
#pragma unroll
    for (int i = 0; i < KSEL; ++i) dst[i] = lst[i];
  }
}

// ---------------- merge: wave per row, 704 = 64 lanes x 11 ----------------
__global__ __launch_bounds__(256) void k_merge(const float* __restrict__ cand,
                                               float* __restrict__ out) {
  int w = threadIdx.x >> 6, lane = threadIdx.x & 63;
  int row = blockIdx.x * 4 + w;
  const float* src = cand + (size_t)row * (PPART * KSEL) + lane * KSEL;
  float lst[KSEL];
#pragma unroll
  for (int i = 0; i < KSEL; ++i) lst[i] = src[i];
#pragma unroll
  for (int s = 1; s <= 32; s <<= 1) {
    float other[KSEL];
#pragma unroll
    for (int j = 0; j < KSEL; ++j) other[j] = __shfl_xor(lst[j], s);
#pragma unroll
    for (int j = 0; j < KSEL; ++j) bins11(other[j], lst);
  }
  if (lane == 0) {
    // lst sorted ascending: lst[0] is the self-match -> dropped
    float s = 0.0f;
#pragma unroll
    for (int j = 1; j < KSEL; ++j) s += sqrtf(fmaxf(lst[j], 0.0f));
    out[row] = log1pf(s * 0.1f);      // mean over k=10, log1p
  }
}

extern "C" void kernel_launch(void* const* d_in, const int* in_sizes, int n_in,
                              void* d_out, int out_size, void* d_ws, size_t ws_size,
                              hipStream_t stream) {
  (void)in_sizes; (void)n_in; (void)out_size; (void)ws_size;
  const float* x   = (const float*)d_in[0];   // 2048 x 64
  const float* buf = (const float*)d_in[1];   // 131072 x 64
  float* out = (float*)d_out;

  char* ws = (char*)d_ws;
  _Float16* B16 = (_Float16*)ws;                       // 16,777,216 B
  float* bnorm  = (float*)(ws + 16777216);             //    524,288 B
  float* cand   = (float*)(ws + 17301504);             //  5,767,168 B

  k_prep_b<<<dim3(2048), dim3(256), 0, stream>>>(buf, B16, bnorm);
  k_main<<<dim3(PPART, NR / ROWS_PER_BLOCK), dim3(256), 0, stream>>>(x, B16, bnorm, cand);
  k_merge<<<dim3(NR / 4), dim3(256), 0, stream>>>(cand, out);
}

// Round 8
// 231.446 us; speedup vs baseline: 1.5232x; 1.5232x over previous
//
#include <hip/hip_runtime.h>
#include <math.h>

// Problem constants (fixed by reference)
#define NR 2048
#define MC 131072
#define DIM 64
#define KSEL 11                    // k+1 smallest kept per row
#define PPART 64                   // column partitions
#define PART_COLS (MC / PPART)     // 2048 cols per partition
#define CHUNK 128                  // cols per LDS chunk
#define NCHUNK (PART_COLS / CHUNK) // 16
#define ROWS_PER_BLOCK 64          // 4 waves x 16 rows
#define QSTR 34                    // queue stride in halves = 17 dwords (odd -> all 32 banks)
#define BSTRIDE 72                 // padded f16 col stride in LDS (144B, 16B-aligned)

typedef _Float16 v8h __attribute__((ext_vector_type(8)));
typedef _Float16 v2h __attribute__((ext_vector_type(2)));
typedef float v4f __attribute__((ext_vector_type(4)));

// ---------------- prep: bnorm (fp32) + buf -> f16 ----------------
__global__ __launch_bounds__(256) void k_prep_b(const float* __restrict__ buf,
                                                _Float16* __restrict__ B16,
                                                float* __restrict__ bnorm) {
  int gid = blockIdx.x * 256 + threadIdx.x;   // 4 threads per buffer row
  int row = gid >> 2, q = gid & 3;
  const float4* src = (const float4*)(buf + (size_t)row * DIM + q * 16);
  float4 f0 = src[0], f1 = src[1], f2 = src[2], f3 = src[3];
  float s = f0.x*f0.x + f0.y*f0.y + f0.z*f0.z + f0.w*f0.w
          + f1.x*f1.x + f1.y*f1.y + f1.z*f1.z + f1.w*f1.w
          + f2.x*f2.x + f2.y*f2.y + f2.z*f2.z + f2.w*f2.w
          + f3.x*f3.x + f3.y*f3.y + f3.z*f3.z + f3.w*f3.w;
  s += __shfl_xor(s, 1);
  s += __shfl_xor(s, 2);
  if (q == 0) bnorm[row] = s;
  union { _Float16 h[16]; uint4 u[2]; } o;
  o.h[0]=(_Float16)f0.x; o.h[1]=(_Float16)f0.y; o.h[2]=(_Float16)f0.z; o.h[3]=(_Float16)f0.w;
  o.h[4]=(_Float16)f1.x; o.h[5]=(_Float16)f1.y; o.h[6]=(_Float16)f1.z; o.h[7]=(_Float16)f1.w;
  o.h[8]=(_Float16)f2.x; o.h[9]=(_Float16)f2.y; o.h[10]=(_Float16)f2.z; o.h[11]=(_Float16)f2.w;
  o.h[12]=(_Float16)f3.x; o.h[13]=(_Float16)f3.y; o.h[14]=(_Float16)f3.z; o.h[15]=(_Float16)f3.w;
  uint4* dst = (uint4*)(B16 + (size_t)row * DIM + q * 16);
  dst[0] = o.u[0]; dst[1] = o.u[1];
}

// branchless bubble-insert into sorted-ascending 11-list. Inserting any value
// >= lst[10] (incl. +inf) is a no-op (it bubbles off the end). 22 min/max ops.
__device__ __forceinline__ void bins11(float v, float lst[KSEL]) {
  float t = v;
#pragma unroll
  for (int j = 0; j < KSEL; ++j) {
    float a = fminf(lst[j], t);
    t = fmaxf(lst[j], t);
    lst[j] = a;
  }
}

// ---------------- main: MFMA + f16 queue + sorted top-11 ---------------------
// D = A(bufcols) x B(xrows): C-layout gives each lane ONE x-row (n = lane&15).
// LDS staging is software-pipelined: chunk c+1's global loads are issued right
// after chunk c is staged, so their latency hides behind c's MFMA/scan/drain.
// Scan pushes t = bn - 2*dot (f16) into a lane-private LDS queue (stride 34
// halves = 17 dwords -> all 32 banks); cap 32 = max pushes/chunk, no overflow.
__global__ __launch_bounds__(256) void k_main(const float* __restrict__ x,
                                              const _Float16* __restrict__ B16,
                                              const float* __restrict__ bnorm,
                                              float* __restrict__ cand) {
  __shared__ __align__(16) _Float16 Bs[CHUNK * BSTRIDE];   // 18432 B
  __shared__ float bns[CHUNK];                             //   512 B
  __shared__ __align__(8) _Float16 qmem[4][64 * QSTR];     // 17408 B -> 36352 B

  const int tid = threadIdx.x;
  const int w = tid >> 6, lane = tid & 63;
  const int quad = lane >> 4, l15 = lane & 15;
  const int row = blockIdx.y * ROWS_PER_BLOCK + w * 16 + l15;  // this lane's x-row
  const int pbase = blockIdx.x * PART_COLS;
  _Float16* q = &qmem[w][lane * QSTR];

  // x fragments (B-operand: B[k = quad*8+j + 32ks][n = l15]) + exact fp32 norm
  v8h bx0, bx1;
  float xn;
  {
    const float* xr = x + (size_t)row * DIM;
    const float4* xp0 = (const float4*)(xr + quad * 8);
    float4 a0 = xp0[0], a1 = xp0[1];
    const float4* xp1 = (const float4*)(xr + 32 + quad * 8);
    float4 c0 = xp1[0], c1 = xp1[1];
    v8h h0, h1;
    h0[0]=(_Float16)a0.x; h0[1]=(_Float16)a0.y; h0[2]=(_Float16)a0.z; h0[3]=(_Float16)a0.w;
    h0[4]=(_Float16)a1.x; h0[5]=(_Float16)a1.y; h0[6]=(_Float16)a1.z; h0[7]=(_Float16)a1.w;
    h1[0]=(_Float16)c0.x; h1[1]=(_Float16)c0.y; h1[2]=(_Float16)c0.z; h1[3]=(_Float16)c0.w;
    h1[4]=(_Float16)c1.x; h1[5]=(_Float16)c1.y; h1[6]=(_Float16)c1.z; h1[7]=(_Float16)c1.w;
    bx0 = h0; bx1 = h1;
    float s = a0.x*a0.x + a0.y*a0.y + a0.z*a0.z + a0.w*a0.w
            + a1.x*a1.x + a1.y*a1.y + a1.z*a1.z + a1.w*a1.w
            + c0.x*c0.x + c0.y*c0.y + c0.z*c0.z + c0.w*c0.w
            + c1.x*c1.x + c1.y*c1.y + c1.z*c1.z + c1.w*c1.w;
    s += __shfl_xor(s, 16);   // each quad holds a disjoint 16 of the 64 k's
    s += __shfl_xor(s, 32);
    xn = s;
  }

  float lst[KSEL];   // sorted ascending; lst[10] = private threshold
#pragma unroll
  for (int i = 0; i < KSEL; ++i) lst[i] = __builtin_inff();
  float thrx = __builtin_inff();   // (shared row thr) - xn, for the scan compare

  // staging-prefetch registers (chunk c+1 loaded during chunk c's compute)
  const int scol = tid >> 1, shf = tid & 1;   // 2 threads/col, 32 f16 each
  uint4 pv0, pv1, pv2, pv3;
  float pbn;
  {
    const uint4* src = (const uint4*)(B16 + (size_t)(pbase + scol) * DIM + shf * 32);
    pv0 = src[0]; pv1 = src[1]; pv2 = src[2]; pv3 = src[3];
    pbn = bnorm[pbase + (tid & (CHUNK - 1))];
  }

  for (int c = 0; c < NCHUNK; ++c) {
    const int cb = pbase + c * CHUNK;
    __syncthreads();   // Bs free (all waves done with previous chunk's reads)
    {
      uint4* dst = (uint4*)(Bs + scol * BSTRIDE + shf * 32);
      dst[0] = pv0; dst[1] = pv1; dst[2] = pv2; dst[3] = pv3;
      if (tid < CHUNK) bns[tid] = pbn;
    }
    __syncthreads();   // staged

    // issue next chunk's loads now; latency hides behind scan+drain below
    if (c + 1 < NCHUNK) {
      const int nb = cb + CHUNK;
      const uint4* src = (const uint4*)(B16 + (size_t)(nb + scol) * DIM + shf * 32);
      pv0 = src[0]; pv1 = src[1]; pv2 = src[2]; pv3 = src[3];
      pbn = bnorm[nb + (tid & (CHUNK - 1))];
    }

    int qo = 0;        // queue write index (elements)
#pragma unroll
    for (int mt = 0; mt < 8; ++mt) {
      v8h a0 = *(const v8h*)(Bs + (mt * 16 + l15) * BSTRIDE + quad * 8);
      v8h a1 = *(const v8h*)(Bs + (mt * 16 + l15) * BSTRIDE + 32 + quad * 8);
      v4f acc = (v4f)(0.0f);
      acc = __builtin_amdgcn_mfma_f32_16x16x32_f16(a0, bx0, acc, 0, 0, 0);
      acc = __builtin_amdgcn_mfma_f32_16x16x32_f16(a1, bx1, acc, 0, 0, 0);
      float4 bn4 = *(const float4*)&bns[mt * 16 + quad * 4];
#pragma unroll
      for (int reg = 0; reg < 4; ++reg) {
        float bn = (reg == 0) ? bn4.x : (reg == 1) ? bn4.y : (reg == 2) ? bn4.z : bn4.w;
        float t = fmaf(acc[reg], -2.0f, bn);   // d2 = t + xn
        // branchless push: always write; advance only on pass. Garbage slots
        // are overwritten by later pushes and bounds-guarded at drain.
        q[qo] = (_Float16)t;
        qo += (t < thrx) ? 1 : 0;
      }
    }

    // batched drain: 4 halves per iter via two dword-aligned ds_read_b32
    for (int i = 0; __ballot(i < qo); i += 4) {
      v2h p0 = *(const v2h*)(q + i);       // byte addr = lane*68 + 2i, 4B-aligned
      v2h p1 = *(const v2h*)(q + i + 2);
      float v0 = (float)p0[0] + xn, v1 = (float)p0[1] + xn;
      float v2 = (float)p1[0] + xn, v3 = (float)p1[1] + xn;
      v0 = (i + 0 < qo) ? v0 : __builtin_inff();
      v1 = (i + 1 < qo) ? v1 : __builtin_inff();
      v2 = (i + 2 < qo) ? v2 : __builtin_inff();
      v3 = (i + 3 < qo) ? v3 : __builtin_inff();
      float m = fminf(fminf(v0, v1), fminf(v2, v3));
      if (__ballot(m < lst[KSEL - 1])) {   // any lane improves its list?
        bins11(v0, lst); bins11(v1, lst);  // v >= lst[10] inserts are no-ops
        bins11(v2, lst); bins11(v3, lst);
      }
    }

    // tighten shared threshold: min over the 4 quads holding this row
    float t = fminf(lst[KSEL - 1], __shfl_xor(lst[KSEL - 1], 16));
    thrx = fminf(t, __shfl_xor(t, 32)) - xn;
  }

  // merge the 4 quads' sorted lists (disjoint col subsets of the same row)
#pragma unroll
  for (int s = 16; s <= 32; s <<= 1) {
    float other[KSEL];
#pragma unroll
    for (int j = 0; j < KSEL; ++j) other[j] = __shfl_xor(lst[j], s);
#pragma unroll
    for (int j = 0; j < KSEL; ++j) bins11(other[j], lst);
  }

  if (quad == 0) {   // one writer per row: cand layout [row][part][k], sorted
    float* dst = cand + (size_t)row * (PPART * KSEL) + blockIdx.x * KSEL;
#pragma unroll
    for (int i = 0; i < KSEL; ++i) dst[i] = lst[i];
  }
}

// ---------------- merge: wave per row, 704 = 64 lanes x 11 ----------------
__global__ __launch_bounds__(256) void k_merge(const float* __restrict__ cand,
                                               float* __restrict__ out) {
  int w = threadIdx.x >> 6, lane = threadIdx.x & 63;
  int row = blockIdx.x * 4 + w;
  const float* src = cand + (size_t)row * (PPART * KSEL) + lane * KSEL;
  float lst[KSEL];
#pragma unroll
  for (int i = 0; i < KSEL; ++i) lst[i] = src[i];
#pragma unroll
  for (int s = 1; s <= 32; s <<= 1) {
    float other[KSEL];
#pragma unroll
    for (int j = 0; j < KSEL; ++j) other[j] = __shfl_xor(lst[j], s);
#pragma unroll
    for (int j = 0; j < KSEL; ++j) bins11(other[j], lst);
  }
  if (lane == 0) {
    // lst sorted ascending: lst[0] is the self-match -> dropped
    float s = 0.0f;
#pragma unroll
    for (int j = 1; j < KSEL; ++j) s += sqrtf(fmaxf(lst[j], 0.0f));
    out[row] = log1pf(s * 0.1f);      // mean over k=10, log1p
  }
}

extern "C" void kernel_launch(void* const* d_in, const int* in_sizes, int n_in,
                              void* d_out, int out_size, void* d_ws, size_t ws_size,
                              hipStream_t stream) {
  (void)in_sizes; (void)n_in; (void)out_size; (void)ws_size;
  const float* x   = (const float*)d_in[0];   // 2048 x 64
  const float* buf = (const float*)d_in[1];   // 131072 x 64
  float* out = (float*)d_out;

  char* ws = (char*)d_ws;
  _Float16* B16 = (_Float16*)ws;                       // 16,777,216 B
  float* bnorm  = (float*)(ws + 16777216);             //    524,288 B
  float* cand   = (float*)(ws + 17301504);             //  5,767,168 B

  k_prep_b<<<dim3(2048), dim3(256), 0, stream>>>(buf, B16, bnorm);
  k_main<<<dim3(PPART, NR / ROWS_PER_BLOCK), dim3(256), 0, stream>>>(x, B16, bnorm, cand);
  k_merge<<<dim3(NR / 4), dim3(256), 0, stream>>>(cand, out);
}